// Round 1
// baseline (365.322 us; speedup 1.0000x reference)
//
#include <hip/hip_runtime.h>
#include <stdint.h>

#define Ttok 1024
#define Hdim 2048
#define Idim 1024
#define Enum 16
#define BM   256
#define BK   32

typedef __attribute__((ext_vector_type(8))) short  short8;
typedef __attribute__((ext_vector_type(4))) short  short4v;
typedef __attribute__((ext_vector_type(4))) float  f32x4;

__device__ __forceinline__ unsigned short f2bf(float f) {
    union { float f; uint32_t u; } v; v.f = f;
    uint32_t u = v.u;
    return (unsigned short)((u + 0x7FFFu + ((u >> 16) & 1u)) >> 16);
}

__device__ __forceinline__ void gld_lds16(const void* g, void* l) {
    __builtin_amdgcn_global_load_lds(
        (const __attribute__((address_space(1))) unsigned int*)g,
        (__attribute__((address_space(3))) unsigned int*)l, 16, 0, 0);
}

// ---------------- Router: logits -> softmax -> biased top2 -> scatter ----------------
__global__ __launch_bounds__(256) void k_router(
    const float* __restrict__ x, const float* __restrict__ gw,
    const float* __restrict__ bias,
    unsigned short* __restrict__ xbf, int* __restrict__ counts,
    int* __restrict__ tids, float* __restrict__ tws)
{
    __shared__ __align__(16) float xrow[Hdim];
    __shared__ float lg[Enum];
    const int t = blockIdx.x;
    const float* xr = x + (size_t)t * Hdim;
    unsigned short* xb = xbf + (size_t)t * Hdim;

    for (int i = threadIdx.x; i < Hdim / 4; i += 256) {
        f32x4 v = ((const f32x4*)xr)[i];
        ((f32x4*)xrow)[i] = v;
        ushort4 b;
        b.x = f2bf(v.x); b.y = f2bf(v.y); b.z = f2bf(v.z); b.w = f2bf(v.w);
        ((ushort4*)xb)[i] = b;
    }
    __syncthreads();

    const int lane = threadIdx.x & 63;
    const int wid  = threadIdx.x >> 6;
    for (int e = wid; e < Enum; e += 4) {
        const float* g = gw + (size_t)e * Hdim;
        float s = 0.f;
        for (int j = lane; j < Hdim; j += 64) s += xrow[j] * g[j];
        #pragma unroll
        for (int off = 32; off; off >>= 1) s += __shfl_xor(s, off);
        if (lane == 0) lg[e] = s;
    }
    __syncthreads();

    if (threadIdx.x == 0) {
        float m = lg[0];
        #pragma unroll
        for (int e = 1; e < Enum; ++e) m = fmaxf(m, lg[e]);
        float sc[Enum]; float sum = 0.f;
        #pragma unroll
        for (int e = 0; e < Enum; ++e) { float ex = expf(lg[e] - m); sc[e] = ex; sum += ex; }
        float inv = 1.f / sum;
        #pragma unroll
        for (int e = 0; e < Enum; ++e) sc[e] *= inv;
        // top-2 on biased scores, strict '>' keeps lowest index (lax.top_k tie rule)
        int i0 = 0; float b0 = sc[0] + bias[0];
        #pragma unroll
        for (int e = 1; e < Enum; ++e) { float bb = sc[e] + bias[e]; if (bb > b0) { b0 = bb; i0 = e; } }
        int i1 = -1; float b1 = -1e30f;
        #pragma unroll
        for (int e = 0; e < Enum; ++e) {
            if (e == i0) continue;
            float bb = sc[e] + bias[e]; if (bb > b1) { b1 = bb; i1 = e; }
        }
        float w0 = sc[i0], w1v = sc[i1];
        float winv = 1.f / (w0 + w1v);
        w0 *= winv; w1v *= winv;
        int p0 = atomicAdd(&counts[i0], 1);
        tids[i0 * Ttok + p0] = t; tws[i0 * Ttok + p0] = w0;
        int p1 = atomicAdd(&counts[i1], 1);
        tids[i1 * Ttok + p1] = t; tws[i1 * Ttok + p1] = w1v;
    }
}

// ---------------- Stage 2: He = silu(X@W1) * (X@W3), per expert ----------------
// grid (Idim/32, 4, Enum), block 256 (4 waves; wave w owns rows w*64..w*64+63, all 32 cols)
__global__ __launch_bounds__(256) void k_expert_h(
    const unsigned short* __restrict__ xbf,
    const float* __restrict__ w1, const float* __restrict__ w3,
    const int* __restrict__ counts, const int* __restrict__ tids,
    unsigned short* __restrict__ He)
{
    const int e  = blockIdx.z;
    const int Ne = counts[e];
    const int row0 = blockIdx.y * BM;
    if (row0 >= Ne) return;
    int base = 0;
    for (int j = 0; j < Enum; ++j) if (j < e) base += counts[j];
    const int col0 = blockIdx.x * 32;
    const int lane = threadIdx.x & 63;
    const int wid  = threadIdx.x >> 6;

    __shared__ __align__(16) unsigned short Xs[2][4][BM][8];     // 32 KB [buf][kg][row][8]
    __shared__ __align__(16) unsigned short Ws[2][2][4][32][8];  // 16 KB [buf][mat][kg][col][8]

    // X gather: wave `wid` stages kgroup=wid; instr j covers rows j*64+lane
    const unsigned short* xptr[4];
    #pragma unroll
    for (int j = 0; j < 4; ++j) {
        int r  = row0 + j * 64 + lane;
        int tk = (r < Ne) ? tids[e * Ttok + r] : 0;   // clamp padding rows (masked later)
        xptr[j] = xbf + (size_t)tk * Hdim + wid * 8;
    }
    // W staging: (mat, kg, col) = (lane>>5, wid, lane&31); 8 k-contig f32 -> 1 ds_write_b128
    const int   wmat = lane >> 5;
    const int   wcol = lane & 31;
    const float* wsrc = (wmat ? w3 : w1) + ((size_t)e * Hdim + wid * 8) * Idim + col0 + wcol;

    f32x4 acc1[4][2], acc3[4][2];
    #pragma unroll
    for (int a = 0; a < 4; ++a)
        #pragma unroll
        for (int b = 0; b < 2; ++b) { acc1[a][b] = (f32x4)(0.f); acc3[a][b] = (f32x4)(0.f); }

    const int NK = Hdim / BK; // 64
    { // prologue -> buf 0
        #pragma unroll
        for (int j = 0; j < 4; ++j) gld_lds16(xptr[j], &Xs[0][wid][j * 64][0]);
        float wv[8];
        #pragma unroll
        for (int jj = 0; jj < 8; ++jj) wv[jj] = wsrc[(size_t)jj * Idim];
        short8 wpk;
        #pragma unroll
        for (int jj = 0; jj < 8; ++jj) wpk[jj] = (short)f2bf(wv[jj]);
        *((short8*)&Ws[0][wmat][wid][wcol][0]) = wpk;
    }
    __syncthreads();

    for (int ks = 0; ks < NK; ++ks) {
        const int cur = ks & 1, nxt = cur ^ 1;
        float wv[8];
        if (ks + 1 < NK) {
            #pragma unroll
            for (int j = 0; j < 4; ++j)
                gld_lds16(xptr[j] + (size_t)(ks + 1) * BK, &Xs[nxt][wid][j * 64][0]);
            const float* wp = wsrc + (size_t)(ks + 1) * BK * Idim;
            #pragma unroll
            for (int jj = 0; jj < 8; ++jj) wv[jj] = wp[(size_t)jj * Idim];
        }
        short8 b1f[2], b3f[2];
        #pragma unroll
        for (int fc = 0; fc < 2; ++fc) {
            b1f[fc] = *(const short8*)&Ws[cur][0][lane >> 4][fc * 16 + (lane & 15)][0];
            b3f[fc] = *(const short8*)&Ws[cur][1][lane >> 4][fc * 16 + (lane & 15)][0];
        }
        #pragma unroll
        for (int fr = 0; fr < 4; ++fr) {
            short8 a = *(const short8*)&Xs[cur][lane >> 4][wid * 64 + fr * 16 + (lane & 15)][0];
            #pragma unroll
            for (int fc = 0; fc < 2; ++fc) {
                acc1[fr][fc] = __builtin_amdgcn_mfma_f32_16x16x32_bf16(a, b1f[fc], acc1[fr][fc], 0, 0, 0);
                acc3[fr][fc] = __builtin_amdgcn_mfma_f32_16x16x32_bf16(a, b3f[fc], acc3[fr][fc], 0, 0, 0);
            }
        }
        if (ks + 1 < NK) {
            short8 wpk;
            #pragma unroll
            for (int jj = 0; jj < 8; ++jj) wpk[jj] = (short)f2bf(wv[jj]);
            *((short8*)&Ws[nxt][wmat][wid][wcol][0]) = wpk;
        }
        __syncthreads();
    }

    // epilogue: he = silu(h1)*h3 -> bf16 He (compact rows), mask padding
    #pragma unroll
    for (int fr = 0; fr < 4; ++fr) {
        int rbase = wid * 64 + fr * 16 + ((lane >> 4) << 2);
        #pragma unroll
        for (int fc = 0; fc < 2; ++fc) {
            int col = col0 + fc * 16 + (lane & 15);
            #pragma unroll
            for (int k = 0; k < 4; ++k) {
                int grow = row0 + rbase + k;
                if (grow < Ne) {
                    float h1 = acc1[fr][fc][k];
                    float h3 = acc3[fr][fc][k];
                    float he = h1 * h3 / (1.f + expf(-h1));
                    He[(size_t)(base + grow) * Idim + col] = f2bf(he);
                }
            }
        }
    }
}

// ---------------- Stage 3: out += w * (He @ W2), per expert ----------------
// grid (Hdim/32, 4, Enum), block 256
__global__ __launch_bounds__(256) void k_expert_o(
    const unsigned short* __restrict__ He,
    const float* __restrict__ w2,
    const int* __restrict__ counts, const int* __restrict__ tids,
    const float* __restrict__ tws,
    float* __restrict__ out)
{
    const int e  = blockIdx.z;
    const int Ne = counts[e];
    const int row0 = blockIdx.y * BM;
    if (row0 >= Ne) return;
    int base = 0;
    for (int j = 0; j < Enum; ++j) if (j < e) base += counts[j];
    const int col0 = blockIdx.x * 32;
    const int lane = threadIdx.x & 63;
    const int wid  = threadIdx.x >> 6;

    __shared__ __align__(16) unsigned short Hs[2][4][BM][8];   // 32 KB
    __shared__ __align__(16) unsigned short W2s[2][4][32][8];  // 8 KB

    const unsigned short* hptr[4];
    #pragma unroll
    for (int j = 0; j < 4; ++j)
        hptr[j] = He + (size_t)(base + row0 + j * 64 + lane) * Idim + wid * 8;

    const int   wcol = lane & 31;
    const int   wsub = lane >> 5;
    const float* wsrc = w2 + ((size_t)e * Idim + wid * 8 + wsub * 4) * Hdim + col0 + wcol;

    f32x4 acc[4][2];
    #pragma unroll
    for (int a = 0; a < 4; ++a)
        #pragma unroll
        for (int b = 0; b < 2; ++b) acc[a][b] = (f32x4)(0.f);

    const int NK = Idim / BK; // 32
    { // prologue
        #pragma unroll
        for (int j = 0; j < 4; ++j) gld_lds16(hptr[j], &Hs[0][wid][j * 64][0]);
        float wv[4];
        #pragma unroll
        for (int jj = 0; jj < 4; ++jj) wv[jj] = wsrc[(size_t)jj * Hdim];
        short4v wpk;
        #pragma unroll
        for (int jj = 0; jj < 4; ++jj) wpk[jj] = (short)f2bf(wv[jj]);
        *((short4v*)&W2s[0][wid][wcol][wsub * 4]) = wpk;
    }
    __syncthreads();

    for (int ks = 0; ks < NK; ++ks) {
        const int cur = ks & 1, nxt = cur ^ 1;
        float wv[4];
        if (ks + 1 < NK) {
            #pragma unroll
            for (int j = 0; j < 4; ++j)
                gld_lds16(hptr[j] + (size_t)(ks + 1) * BK, &Hs[nxt][wid][j * 64][0]);
            const float* wp = wsrc + (size_t)(ks + 1) * BK * Hdim;
            #pragma unroll
            for (int jj = 0; jj < 4; ++jj) wv[jj] = wp[(size_t)jj * Hdim];
        }
        short8 bf[2];
        #pragma unroll
        for (int fc = 0; fc < 2; ++fc)
            bf[fc] = *(const short8*)&W2s[cur][lane >> 4][fc * 16 + (lane & 15)][0];
        #pragma unroll
        for (int fr = 0; fr < 4; ++fr) {
            short8 a = *(const short8*)&Hs[cur][lane >> 4][wid * 64 + fr * 16 + (lane & 15)][0];
            #pragma unroll
            for (int fc = 0; fc < 2; ++fc)
                acc[fr][fc] = __builtin_amdgcn_mfma_f32_16x16x32_bf16(a, bf[fc], acc[fr][fc], 0, 0, 0);
        }
        if (ks + 1 < NK) {
            short4v wpk;
            #pragma unroll
            for (int jj = 0; jj < 4; ++jj) wpk[jj] = (short)f2bf(wv[jj]);
            *((short4v*)&W2s[nxt][wid][wcol][wsub * 4]) = wpk;
        }
        __syncthreads();
    }

    #pragma unroll
    for (int fr = 0; fr < 4; ++fr) {
        int rbase = wid * 64 + fr * 16 + ((lane >> 4) << 2);
        #pragma unroll
        for (int k = 0; k < 4; ++k) {
            int grow = row0 + rbase + k;
            if (grow < Ne) {
                int   tk = tids[e * Ttok + grow];
                float w  = tws[e * Ttok + grow];
                #pragma unroll
                for (int fc = 0; fc < 2; ++fc) {
                    int col = col0 + fc * 16 + (lane & 15);
                    atomicAdd(&out[(size_t)tk * Hdim + col], w * acc[fr][fc][k]);
                }
            }
        }
    }
}

extern "C" void kernel_launch(void* const* d_in, const int* in_sizes, int n_in,
                              void* d_out, int out_size, void* d_ws, size_t ws_size,
                              hipStream_t stream)
{
    const float* x    = (const float*)d_in[0];
    const float* gw   = (const float*)d_in[1];
    const float* bias = (const float*)d_in[2];
    const float* w1   = (const float*)d_in[3];
    const float* w3   = (const float*)d_in[4];
    const float* w2   = (const float*)d_in[5];
    float* out = (float*)d_out;

    char* ws = (char*)d_ws;
    int*            counts = (int*)ws;                               // 64 B
    int*            tids   = (int*)(ws + 1024);                      // 64 KB
    float*          tws    = (float*)(ws + 1024 + 65536);            // 64 KB
    unsigned short* xbf    = (unsigned short*)(ws + 262144);         // 4 MB
    unsigned short* He     = (unsigned short*)(ws + 262144 + 4194304); // (2048+256)*1024*2 B

    hipMemsetAsync(counts, 0, Enum * sizeof(int), stream);
    hipMemsetAsync(out, 0, (size_t)Ttok * Hdim * sizeof(float), stream);

    k_router<<<dim3(Ttok), dim3(256), 0, stream>>>(x, gw, bias, xbf, counts, tids, tws);
    k_expert_h<<<dim3(Idim / 32, 4, Enum), dim3(256), 0, stream>>>(xbf, w1, w3, counts, tids, He);
    k_expert_o<<<dim3(Hdim / 32, 4, Enum), dim3(256), 0, stream>>>(He, w2, counts, tids, tws, out);
}

// Round 2
// 237.977 us; speedup vs baseline: 1.5351x; 1.5351x over previous
//
#include <hip/hip_runtime.h>
#include <stdint.h>

#define Ttok 1024
#define Hdim 2048
#define Idim 1024
#define Enum 16
#define BM   128
#define BKs  64

typedef __attribute__((ext_vector_type(8))) short  short8;
typedef __attribute__((ext_vector_type(4))) float  f32x4;

__device__ __forceinline__ unsigned short f2bf(float f) {
    union { float f; uint32_t u; } v; v.f = f;
    uint32_t u = v.u;
    return (unsigned short)((u + 0x7FFFu + ((u >> 16) & 1u)) >> 16);
}

__device__ __forceinline__ void gld_lds16(const void* g, void* l) {
    __builtin_amdgcn_global_load_lds(
        (const __attribute__((address_space(1))) unsigned int*)g,
        (__attribute__((address_space(3))) unsigned int*)l, 16, 0, 0);
}

// ---------------- Router: logits -> softmax -> biased top2 -> scatter ----------------
__global__ __launch_bounds__(256) void k_router(
    const float* __restrict__ x, const float* __restrict__ gw,
    const float* __restrict__ bias,
    unsigned short* __restrict__ xbf, int* __restrict__ counts,
    int* __restrict__ tids, float* __restrict__ tws)
{
    __shared__ __align__(16) float xrow[Hdim];
    __shared__ float lg[Enum];
    const int t = blockIdx.x;
    const float* xr = x + (size_t)t * Hdim;
    unsigned short* xb = xbf + (size_t)t * Hdim;

    for (int i = threadIdx.x; i < Hdim / 4; i += 256) {
        f32x4 v = ((const f32x4*)xr)[i];
        ((f32x4*)xrow)[i] = v;
        ushort4 b;
        b.x = f2bf(v.x); b.y = f2bf(v.y); b.z = f2bf(v.z); b.w = f2bf(v.w);
        ((ushort4*)xb)[i] = b;
    }
    __syncthreads();

    const int lane = threadIdx.x & 63;
    const int wid  = threadIdx.x >> 6;
    for (int e = wid; e < Enum; e += 4) {
        const float* g = gw + (size_t)e * Hdim;
        float s = 0.f;
        for (int j = lane; j < Hdim; j += 64) s += xrow[j] * g[j];
        #pragma unroll
        for (int off = 32; off; off >>= 1) s += __shfl_xor(s, off);
        if (lane == 0) lg[e] = s;
    }
    __syncthreads();

    if (threadIdx.x == 0) {
        float m = lg[0];
        #pragma unroll
        for (int e = 1; e < Enum; ++e) m = fmaxf(m, lg[e]);
        float sc[Enum]; float sum = 0.f;
        #pragma unroll
        for (int e = 0; e < Enum; ++e) { float ex = expf(lg[e] - m); sc[e] = ex; sum += ex; }
        float inv = 1.f / sum;
        #pragma unroll
        for (int e = 0; e < Enum; ++e) sc[e] *= inv;
        int i0 = 0; float b0 = sc[0] + bias[0];
        #pragma unroll
        for (int e = 1; e < Enum; ++e) { float bb = sc[e] + bias[e]; if (bb > b0) { b0 = bb; i0 = e; } }
        int i1 = -1; float b1 = -1e30f;
        #pragma unroll
        for (int e = 0; e < Enum; ++e) {
            if (e == i0) continue;
            float bb = sc[e] + bias[e]; if (bb > b1) { b1 = bb; i1 = e; }
        }
        float w0 = sc[i0], w1v = sc[i1];
        float winv = 1.f / (w0 + w1v);
        w0 *= winv; w1v *= winv;
        int p0 = atomicAdd(&counts[i0], 1);
        tids[i0 * Ttok + p0] = t; tws[i0 * Ttok + p0] = w0;
        int p1 = atomicAdd(&counts[i1], 1);
        tids[i1 * Ttok + p1] = t; tws[i1 * Ttok + p1] = w1v;
    }
}

// ---------------- Stage 2: He = silu(X@W1) * (X@W3) ----------------
// grid (Idim/32=32, 8, Enum), block 256. BM=128, BK=64, N=32 (x2 mats).
__global__ __launch_bounds__(256) void k_expert_h(
    const unsigned short* __restrict__ xbf,
    const float* __restrict__ w1, const float* __restrict__ w3,
    const int* __restrict__ counts, const int* __restrict__ tids,
    unsigned short* __restrict__ He)
{
    const int e  = blockIdx.z;
    const int Ne = counts[e];
    const int row0 = blockIdx.y * BM;
    if (row0 >= Ne) return;
    int base = 0;
    for (int j = 0; j < Enum; ++j) if (j < e) base += counts[j];
    const int col0 = blockIdx.x * 32;
    const int lane = threadIdx.x & 63;
    const int wid  = threadIdx.x >> 6;

    __shared__ __align__(16) unsigned short Xs[2][8][BM][8];    // 32 KB [buf][kg][row][8]
    __shared__ __align__(16) unsigned short Ws[2][2][8][32][8]; // 16 KB [buf][mat][kg][col][8]

    // X gather: wave wid stages kg in {2wid,2wid+1}, rowhalves rh in {0,1}
    const unsigned short* xptr[2];
    #pragma unroll
    for (int rh = 0; rh < 2; ++rh) {
        int r  = row0 + rh * 64 + lane;
        int tk = (r < Ne) ? tids[e * Ttok + r] : 0;
        xptr[rh] = xbf + (size_t)tk * Hdim + wid * 16; // kg0 = 2*wid -> 16 halfs
    }
    // W staging: mat = tid>>7, kg = (tid>>4)&7, colgroup cg = tid&15 (cols 2cg,2cg+1)
    const int wmat = threadIdx.x >> 7;
    const int wkg  = (threadIdx.x >> 4) & 7;
    const int wcg  = threadIdx.x & 15;
    const float* wsrc = (wmat ? w3 : w1) + ((size_t)e * Hdim + wkg * 8) * Idim + col0 + wcg * 2;

    f32x4 acc1[2][2], acc3[2][2];
    #pragma unroll
    for (int a = 0; a < 2; ++a)
        #pragma unroll
        for (int b = 0; b < 2; ++b) { acc1[a][b] = (f32x4)(0.f); acc3[a][b] = (f32x4)(0.f); }

    const int NK = Hdim / BKs; // 32
    { // prologue -> buf 0
        #pragma unroll
        for (int rh = 0; rh < 2; ++rh)
            #pragma unroll
            for (int kk = 0; kk < 2; ++kk)
                gld_lds16(xptr[rh] + kk * 8, &Xs[0][wid * 2 + kk][rh * 64][0]);
        float2 wv[8];
        #pragma unroll
        for (int jj = 0; jj < 8; ++jj) wv[jj] = *(const float2*)(wsrc + (size_t)jj * Idim);
        short8 p0, p1;
        #pragma unroll
        for (int jj = 0; jj < 8; ++jj) { p0[jj] = (short)f2bf(wv[jj].x); p1[jj] = (short)f2bf(wv[jj].y); }
        *((short8*)&Ws[0][wmat][wkg][wcg * 2][0])     = p0;
        *((short8*)&Ws[0][wmat][wkg][wcg * 2 + 1][0]) = p1;
    }
    __syncthreads();

    for (int ks = 0; ks < NK; ++ks) {
        const int cur = ks & 1, nxt = cur ^ 1;
        float2 wv[8];
        if (ks + 1 < NK) {
            #pragma unroll
            for (int rh = 0; rh < 2; ++rh)
                #pragma unroll
                for (int kk = 0; kk < 2; ++kk)
                    gld_lds16(xptr[rh] + (size_t)(ks + 1) * BKs + kk * 8,
                              &Xs[nxt][wid * 2 + kk][rh * 64][0]);
            const float* wp = wsrc + (size_t)(ks + 1) * BKs * Idim;
            #pragma unroll
            for (int jj = 0; jj < 8; ++jj) wv[jj] = *(const float2*)(wp + (size_t)jj * Idim);
        }
        #pragma unroll
        for (int ks2 = 0; ks2 < 2; ++ks2) {
            const int kgi = ks2 * 4 + (lane >> 4);
            short8 a[2], b1[2], b3[2];
            #pragma unroll
            for (int fr = 0; fr < 2; ++fr)
                a[fr] = *(const short8*)&Xs[cur][kgi][wid * 32 + fr * 16 + (lane & 15)][0];
            #pragma unroll
            for (int fc = 0; fc < 2; ++fc) {
                b1[fc] = *(const short8*)&Ws[cur][0][kgi][fc * 16 + (lane & 15)][0];
                b3[fc] = *(const short8*)&Ws[cur][1][kgi][fc * 16 + (lane & 15)][0];
            }
            #pragma unroll
            for (int fr = 0; fr < 2; ++fr)
                #pragma unroll
                for (int fc = 0; fc < 2; ++fc) {
                    acc1[fr][fc] = __builtin_amdgcn_mfma_f32_16x16x32_bf16(a[fr], b1[fc], acc1[fr][fc], 0, 0, 0);
                    acc3[fr][fc] = __builtin_amdgcn_mfma_f32_16x16x32_bf16(a[fr], b3[fc], acc3[fr][fc], 0, 0, 0);
                }
        }
        if (ks + 1 < NK) {
            short8 p0, p1;
            #pragma unroll
            for (int jj = 0; jj < 8; ++jj) { p0[jj] = (short)f2bf(wv[jj].x); p1[jj] = (short)f2bf(wv[jj].y); }
            *((short8*)&Ws[nxt][wmat][wkg][wcg * 2][0])     = p0;
            *((short8*)&Ws[nxt][wmat][wkg][wcg * 2 + 1][0]) = p1;
        }
        __syncthreads();
    }

    // epilogue: he = silu(h1)*h3 -> bf16 He (compact rows), mask padding
    #pragma unroll
    for (int fr = 0; fr < 2; ++fr) {
        int rbase = wid * 32 + fr * 16 + ((lane >> 4) << 2);
        #pragma unroll
        for (int fc = 0; fc < 2; ++fc) {
            int col = col0 + fc * 16 + (lane & 15);
            #pragma unroll
            for (int k = 0; k < 4; ++k) {
                int grow = row0 + rbase + k;
                if (grow < Ne) {
                    float h1 = acc1[fr][fc][k];
                    float h3 = acc3[fr][fc][k];
                    float he = h1 * h3 / (1.f + expf(-h1));
                    He[(size_t)(base + grow) * Idim + col] = f2bf(he);
                }
            }
        }
    }
}

// ---------------- Stage 3: out += w * (He @ W2) ----------------
// grid (Hdim/64=32, 8, Enum), block 256. BM=128, BK=64, BN=64.
__global__ __launch_bounds__(256) void k_expert_o(
    const unsigned short* __restrict__ He,
    const float* __restrict__ w2,
    const int* __restrict__ counts, const int* __restrict__ tids,
    const float* __restrict__ tws,
    float* __restrict__ out)
{
    const int e  = blockIdx.z;
    const int Ne = counts[e];
    const int row0 = blockIdx.y * BM;
    if (row0 >= Ne) return;
    int base = 0;
    for (int j = 0; j < Enum; ++j) if (j < e) base += counts[j];
    const int col0 = blockIdx.x * 64;
    const int lane = threadIdx.x & 63;
    const int wid  = threadIdx.x >> 6;

    __shared__ __align__(16) unsigned short Hs[2][8][BM][8];  // 32 KB
    __shared__ __align__(16) unsigned short W2s[2][8][64][8]; // 16 KB

    const unsigned short* hptr[2];
    #pragma unroll
    for (int rh = 0; rh < 2; ++rh)
        hptr[rh] = He + (size_t)(base + row0 + rh * 64 + lane) * Idim + wid * 16;

    // W2: kg = tid>>5 (8 kg of 8k), colgroup cg = tid&31 (cols 2cg,2cg+1)
    const int wkg = threadIdx.x >> 5;
    const int wcg = threadIdx.x & 31;
    const float* wsrc = w2 + ((size_t)e * Idim + wkg * 8) * Hdim + col0 + wcg * 2;

    f32x4 acc[2][4];
    #pragma unroll
    for (int a = 0; a < 2; ++a)
        #pragma unroll
        for (int b = 0; b < 4; ++b) acc[a][b] = (f32x4)(0.f);

    const int NK = Idim / BKs; // 16
    { // prologue
        #pragma unroll
        for (int rh = 0; rh < 2; ++rh)
            #pragma unroll
            for (int kk = 0; kk < 2; ++kk)
                gld_lds16(hptr[rh] + kk * 8, &Hs[0][wid * 2 + kk][rh * 64][0]);
        float2 wv[8];
        #pragma unroll
        for (int jj = 0; jj < 8; ++jj) wv[jj] = *(const float2*)(wsrc + (size_t)jj * Hdim);
        short8 p0, p1;
        #pragma unroll
        for (int jj = 0; jj < 8; ++jj) { p0[jj] = (short)f2bf(wv[jj].x); p1[jj] = (short)f2bf(wv[jj].y); }
        *((short8*)&W2s[0][wkg][wcg * 2][0])     = p0;
        *((short8*)&W2s[0][wkg][wcg * 2 + 1][0]) = p1;
    }
    __syncthreads();

    for (int ks = 0; ks < NK; ++ks) {
        const int cur = ks & 1, nxt = cur ^ 1;
        float2 wv[8];
        if (ks + 1 < NK) {
            #pragma unroll
            for (int rh = 0; rh < 2; ++rh)
                #pragma unroll
                for (int kk = 0; kk < 2; ++kk)
                    gld_lds16(hptr[rh] + (size_t)(ks + 1) * BKs + kk * 8,
                              &Hs[nxt][wid * 2 + kk][rh * 64][0]);
            const float* wp = wsrc + (size_t)(ks + 1) * BKs * Hdim;
            #pragma unroll
            for (int jj = 0; jj < 8; ++jj) wv[jj] = *(const float2*)(wp + (size_t)jj * Hdim);
        }
        #pragma unroll
        for (int ks2 = 0; ks2 < 2; ++ks2) {
            const int kgi = ks2 * 4 + (lane >> 4);
            short8 a[2], b[4];
            #pragma unroll
            for (int fr = 0; fr < 2; ++fr)
                a[fr] = *(const short8*)&Hs[cur][kgi][wid * 32 + fr * 16 + (lane & 15)][0];
            #pragma unroll
            for (int fc = 0; fc < 4; ++fc)
                b[fc] = *(const short8*)&W2s[cur][kgi][fc * 16 + (lane & 15)][0];
            #pragma unroll
            for (int fr = 0; fr < 2; ++fr)
                #pragma unroll
                for (int fc = 0; fc < 4; ++fc)
                    acc[fr][fc] = __builtin_amdgcn_mfma_f32_16x16x32_bf16(a[fr], b[fc], acc[fr][fc], 0, 0, 0);
        }
        if (ks + 1 < NK) {
            short8 p0, p1;
            #pragma unroll
            for (int jj = 0; jj < 8; ++jj) { p0[jj] = (short)f2bf(wv[jj].x); p1[jj] = (short)f2bf(wv[jj].y); }
            *((short8*)&W2s[nxt][wkg][wcg * 2][0])     = p0;
            *((short8*)&W2s[nxt][wkg][wcg * 2 + 1][0]) = p1;
        }
        __syncthreads();
    }

    #pragma unroll
    for (int fr = 0; fr < 2; ++fr) {
        int rbase = wid * 32 + fr * 16 + ((lane >> 4) << 2);
        #pragma unroll
        for (int k = 0; k < 4; ++k) {
            int grow = row0 + rbase + k;
            if (grow < Ne) {
                int   tk = tids[e * Ttok + grow];
                float w  = tws[e * Ttok + grow];
                #pragma unroll
                for (int fc = 0; fc < 4; ++fc) {
                    int col = col0 + fc * 16 + (lane & 15);
                    atomicAdd(&out[(size_t)tk * Hdim + col], w * acc[fr][fc][k]);
                }
            }
        }
    }
}

extern "C" void kernel_launch(void* const* d_in, const int* in_sizes, int n_in,
                              void* d_out, int out_size, void* d_ws, size_t ws_size,
                              hipStream_t stream)
{
    const float* x    = (const float*)d_in[0];
    const float* gw   = (const float*)d_in[1];
    const float* bias = (const float*)d_in[2];
    const float* w1   = (const float*)d_in[3];
    const float* w3   = (const float*)d_in[4];
    const float* w2   = (const float*)d_in[5];
    float* out = (float*)d_out;

    char* ws = (char*)d_ws;
    int*            counts = (int*)ws;                                 // 64 B
    int*            tids   = (int*)(ws + 1024);                        // 64 KB
    float*          tws    = (float*)(ws + 1024 + 65536);              // 64 KB
    unsigned short* xbf    = (unsigned short*)(ws + 262144);           // 4 MB
    unsigned short* He     = (unsigned short*)(ws + 262144 + 4194304); // (2048+256)*1024*2 B

    hipMemsetAsync(counts, 0, Enum * sizeof(int), stream);
    hipMemsetAsync(out, 0, (size_t)Ttok * Hdim * sizeof(float), stream);

    k_router<<<dim3(Ttok), dim3(256), 0, stream>>>(x, gw, bias, xbf, counts, tids, tws);
    k_expert_h<<<dim3(Idim / 32, 8, Enum), dim3(256), 0, stream>>>(xbf, w1, w3, counts, tids, He);
    k_expert_o<<<dim3(Hdim / 64, 8, Enum), dim3(256), 0, stream>>>(He, w2, counts, tids, tws, out);
}